// Round 7
// baseline (589.911 us; speedup 1.0000x reference)
//
#include <hip/hip_runtime.h>

// YOLO-style loss: pred/target (bs, 7, 7, 30) fp32 -> scalar.
// S=7, B=2 boxes (5 ch each), C=20 classes. Memory-bound streaming reduction.
//
// v6b = v5 + NON-TEMPORAL loads (only change; clean A/B vs round 5).
// (v6a failed to compile: __builtin_nontemporal_load rejects
//  HIP_vector_type<float,4>* -- it needs a NATIVE clang vector type. Fixed
//  by loading through float __attribute__((ext_vector_type(4))).)
//
// Rationale: four structurally different kernels (LDS-staged coalesced /
// divergent float2 / sweep+gather / divergent float4) all plateau at the
// SAME demand rate 3.0+-0.2 TB/s while nothing is at its ceiling (HBM
// 1.5-2.3 of 6.3 TB/s, VALU <12%, L1 txn counts vary 16x with no effect).
// The one quantity identical across versions is L1 line FILLS (read-once:
// each 64B line filled exactly once per dispatch). Theory: per-CU L1
// fill-rate cap. Test: global_load_dwordx4 nt bypasses L1 retention.
// If the theory holds this jumps toward ~80 us; if unchanged, the cap is
// below L2 and we are at this op's structural ceiling.
//
// Structure (unchanged from v5): cell-PAIR per thread, 2 cells = 240 B =
// 15 float4s per tensor, compile-time slot mapping, all-register box/IoU
// math (v2's exact arithmetic, absmax 0.0), wave shuffle + LDS reduce.
// Pass 2: single block reduces per-block partials -> out[0]. Deterministic.
// Fallback (ws too small): zero-init + one atomicAdd per block.

#define CH 30
#define SDIV 7.0f

typedef float vfloat4 __attribute__((ext_vector_type(4)));

__device__ __forceinline__ float4 ldnt4(const float* __restrict__ p) {
    const vfloat4 v = __builtin_nontemporal_load(
        reinterpret_cast<const vfloat4*>(p));
    return make_float4(v.x, v.y, v.z, v.w);
}

// Box/conf/IoU loss for one cell given its 10 box floats (ch 0..9) of pred
// and target, all constant-indexed. Returns obj flag via obj_out.
__device__ __forceinline__ float box_loss(const float p[10], const float t[10],
                                          float& obj_out)
{
    const float obj   = (t[4] > 0.0f) ? 1.0f : 0.0f;
    obj_out = obj;
    const float noobj = 1.0f - obj;

    const float d4 = p[4] - t[4];
    const float d9 = p[9] - t[9];
    const float l_noobj = d4 * d4 + d9 * d9;

    // target box 0 -> xyxy (matches reference op order)
    const float t_x0 = t[0] / SDIV - 0.5f * t[2];
    const float t_y0 = t[1] / SDIV - 0.5f * t[3];
    const float t_x1 = t[0] / SDIV + 0.5f * t[2];
    const float t_y1 = t[1] / SDIV + 0.5f * t[3];
    const float area_t = (t_x1 - t_x0) * (t_y1 - t_y0);

    float iou0, iou1;
    #pragma unroll
    for (int b = 0; b < 2; ++b) {
        const float bx0 = b ? p[5] : p[0];
        const float bx1 = b ? p[6] : p[1];
        const float bx2 = b ? p[7] : p[2];
        const float bx3 = b ? p[8] : p[3];
        const float x0 = bx0 / SDIV - 0.5f * bx2;
        const float y0 = bx1 / SDIV - 0.5f * bx3;
        const float x1 = bx0 / SDIV + 0.5f * bx2;
        const float y1 = bx1 / SDIV + 0.5f * bx3;
        const float ltx = fmaxf(x0, t_x0);
        const float lty = fmaxf(y0, t_y0);
        const float rbx = fminf(x1, t_x1);
        const float rby = fminf(y1, t_y1);
        const float w = fmaxf(rbx - ltx, 0.0f);
        const float h = fmaxf(rby - lty, 0.0f);
        const float inter  = w * h;
        const float area_p = (x1 - x0) * (y1 - y0);
        const float uni = fmaxf(area_p + area_t - inter, 1e-10f);
        const float iou = inter / uni;
        if (b == 0) iou0 = iou; else iou1 = iou;
    }

    // jnp.argmax picks first on ties -> box1 only if strictly greater
    const bool  bsel    = (iou1 > iou0);
    const float max_iou = bsel ? iou1 : iou0;

    const float prx = bsel ? p[5] : p[0];
    const float pry = bsel ? p[6] : p[1];
    const float prw = bsel ? p[7] : p[2];
    const float prh = bsel ? p[8] : p[3];
    const float prc = bsel ? p[9] : p[4];
    const float trx = bsel ? t[5] : t[0];
    const float try_ = bsel ? t[6] : t[1];
    const float trw = bsel ? t[7] : t[2];
    const float trh = bsel ? t[8] : t[3];

    const float dx = prx - trx;
    const float dy = pry - try_;
    const float l_xy = dx * dx + dy * dy;
    const float dw = sqrtf(prw) - sqrtf(trw);
    const float dh = sqrtf(prh) - sqrtf(trh);
    const float l_wh = dw * dw + dh * dh;
    const float dc = prc - max_iou;
    const float l_obj = dc * dc;

    return obj * (5.0f * (l_xy + l_wh) + l_obj) + 0.5f * noobj * l_noobj;
}

#define SQD(a, b) (((a) - (b)) * ((a) - (b)))

template <bool USE_ATOMIC>
__global__ __launch_bounds__(256) void yolo_loss_pass1(
    const float* __restrict__ pred, const float* __restrict__ tgt,
    float* __restrict__ dst, long long n_cells, float scale)
{
    __shared__ float wsums[4];

    const int tid = threadIdx.x;
    const long long pair  = (long long)blockIdx.x * 256 + tid;
    const long long cellA = 2 * pair;
    const long long cellB = cellA + 1;

    float acc = 0.0f;

    if (cellB < n_cells) {
        // ---- fast path: 15+15 nt float4 loads, all-register, static slots --
        const float* __restrict__ pbase = pred + cellA * CH;
        const float* __restrict__ tbase = tgt  + cellA * CH;

        float4 P[15], T[15];
        #pragma unroll
        for (int i = 0; i < 15; ++i) {
            P[i] = ldnt4(pbase + 4 * i);
            T[i] = ldnt4(tbase + 4 * i);
        }

        // class sums (static slots). Cell A: ch10..29 = f2.zw, f3..f6, f7.xy
        float clsA = SQD(P[2].z, T[2].z) + SQD(P[2].w, T[2].w)
                   + SQD(P[7].x, T[7].x) + SQD(P[7].y, T[7].y);
        #pragma unroll
        for (int i = 3; i <= 6; ++i) {
            clsA += SQD(P[i].x, T[i].x) + SQD(P[i].y, T[i].y)
                  + SQD(P[i].z, T[i].z) + SQD(P[i].w, T[i].w);
        }
        // Cell B: ch10..29 = f10..f14
        float clsB = 0.0f;
        #pragma unroll
        for (int i = 10; i <= 14; ++i) {
            clsB += SQD(P[i].x, T[i].x) + SQD(P[i].y, T[i].y)
                  + SQD(P[i].z, T[i].z) + SQD(P[i].w, T[i].w);
        }

        // box floats (ch 0..9), static slots
        const float pA[10] = {P[0].x, P[0].y, P[0].z, P[0].w,
                              P[1].x, P[1].y, P[1].z, P[1].w,
                              P[2].x, P[2].y};
        const float tA[10] = {T[0].x, T[0].y, T[0].z, T[0].w,
                              T[1].x, T[1].y, T[1].z, T[1].w,
                              T[2].x, T[2].y};
        const float pB[10] = {P[7].z, P[7].w,
                              P[8].x, P[8].y, P[8].z, P[8].w,
                              P[9].x, P[9].y, P[9].z, P[9].w};
        const float tB[10] = {T[7].z, T[7].w,
                              T[8].x, T[8].y, T[8].z, T[8].w,
                              T[9].x, T[9].y, T[9].z, T[9].w};

        float objA, objB;
        acc  = box_loss(pA, tA, objA) + objA * clsA;
        acc += box_loss(pB, tB, objB) + objB * clsB;
    } else if (cellA < n_cells) {
        // ---- tail: single trailing cell (odd n_cells), scalar loads ----
        const float* __restrict__ p = pred + cellA * CH;
        const float* __restrict__ t = tgt  + cellA * CH;
        float pA[10], tA[10];
        #pragma unroll
        for (int c = 0; c < 10; ++c) { pA[c] = p[c]; tA[c] = t[c]; }
        float cls = 0.0f;
        #pragma unroll
        for (int c = 10; c < 30; ++c) cls += SQD(p[c], t[c]);
        float objA;
        acc = box_loss(pA, tA, objA) + objA * cls;
    }

    // ---- reduce: wave64 shuffle -> per-wave LDS -> per-block result ----
    float v = acc;
    #pragma unroll
    for (int off = 32; off > 0; off >>= 1)
        v += __shfl_down(v, off, 64);

    const int wave = tid >> 6;
    const int lane = tid & 63;
    if (lane == 0) wsums[wave] = v;
    __syncthreads();
    if (tid == 0) {
        const float sum = wsums[0] + wsums[1] + wsums[2] + wsums[3];
        if (USE_ATOMIC) atomicAdd(dst, sum * scale);
        else            dst[blockIdx.x] = sum;
    }
}

__global__ __launch_bounds__(256) void yolo_loss_pass2(
    const float* __restrict__ partials, float* __restrict__ out,
    int n_partials, float scale)
{
    __shared__ float wsums[4];
    const int tid = threadIdx.x;

    float v = 0.0f;
    for (int i = tid; i < n_partials; i += 256)
        v += partials[i];

    #pragma unroll
    for (int off = 32; off > 0; off >>= 1)
        v += __shfl_down(v, off, 64);

    const int wave = tid >> 6;
    const int lane = tid & 63;
    if (lane == 0) wsums[wave] = v;
    __syncthreads();
    if (tid == 0)
        out[0] = (wsums[0] + wsums[1] + wsums[2] + wsums[3]) * scale;
}

__global__ __launch_bounds__(64) void zero_out_kernel(float* out) {
    if (threadIdx.x == 0) out[0] = 0.0f;
}

extern "C" void kernel_launch(void* const* d_in, const int* in_sizes, int n_in,
                              void* d_out, int out_size, void* d_ws, size_t ws_size,
                              hipStream_t stream) {
    const float* pred = (const float*)d_in[0];
    const float* tgt  = (const float*)d_in[1];
    float* out = (float*)d_out;
    float* partials = (float*)d_ws;

    const long long total   = (long long)in_sizes[0];
    const long long n_cells = total / CH;          // bs*S*S
    const long long bs      = n_cells / 49;        // S*S = 49
    const float scale = 1.0f / (float)bs;

    // one thread per cell-PAIR; block covers 512 cells
    const int grid = (int)((n_cells + 511) / 512);

    if (ws_size >= (size_t)grid * sizeof(float)) {
        // deterministic two-pass path
        yolo_loss_pass1<false><<<grid, 256, 0, stream>>>(pred, tgt, partials,
                                                         n_cells, scale);
        yolo_loss_pass2<<<1, 256, 0, stream>>>(partials, out, grid, scale);
    } else {
        // fallback: zero-init + one atomic per block
        zero_out_kernel<<<1, 64, 0, stream>>>(out);
        yolo_loss_pass1<true><<<grid, 256, 0, stream>>>(pred, tgt, out,
                                                        n_cells, scale);
    }
}

// Round 8
// 378.997 us; speedup vs baseline: 1.5565x; 1.5565x over previous
//
#include <hip/hip_runtime.h>

// YOLO-style loss: pred/target (bs, 7, 7, 30) fp32 -> scalar.
// S=7, B=2 boxes (5 ch each), C=20 classes. Memory-bound streaming reduction.
//
// v7 = v2 restored (session best: bench 376.6 us, pass1 123.4 us, absmax 0.0).
//
// CEILING MODEL (established over v1/v2/v3/v5/v6b): five structurally
// different kernels (LDS-staged coalesced / divergent float2 / coalesced
// sweep+gather / divergent float4 / nt-bypass) all pin the TCC->CU read-
// return rate at 3.0-3.34 TB/s while occupancy (21-80%), L1 txn count
// (16x), and L3-hit fraction (0-49%) vary freely. The documented 6.3 TB/s
// "achievable" is a float4 COPY = 3.15 read + 3.15 write; the read
// DIRECTION (XCD<->IOD fabric, ~400 GB/s/XCD x 8) caps at ~3.3 TB/s.
// A pure-read single-pass reduction (385 MB demand, no reuse: >> 32MB L2)
// therefore floors at ~117 us/pass. v2 runs 123.4 us = 95% of the
// demonstrated 3.34 TB/s ceiling (v6b sustained it for 312 us straight).
//
// Structure: 1 thread = 1 cell, 15+15 float2 direct loads (8B-aligned,
// 120%8==0), class channels consumed on the fly, all-register box/IoU
// math, wave shuffle + LDS reduce -> one partial per block.
// Pass 2: single block reduces partials -> out[0]. Deterministic.
// Fallback (ws too small): zero-init + one atomicAdd per block.

#define CH 30
#define SDIV 7.0f

__device__ __forceinline__ float2 ld2(const float* __restrict__ p, int off) {
    return *reinterpret_cast<const float2*>(p + off);
}

template <bool USE_ATOMIC>
__global__ __launch_bounds__(256) void yolo_loss_pass1(
    const float* __restrict__ pred, const float* __restrict__ tgt,
    float* __restrict__ dst, long long n_cells, float scale)
{
    __shared__ float wsums[4];

    const int tid = threadIdx.x;
    const long long cell = (long long)blockIdx.x * 256 + tid;

    float cell_loss = 0.0f;
    if (cell < n_cells) {
        const float* __restrict__ p = pred + cell * CH;
        const float* __restrict__ t = tgt  + cell * CH;

        // box channels 0..9 of both tensors (stay live in registers)
        const float2 pa = ld2(p, 0), pb = ld2(p, 2), pc = ld2(p, 4),
                     pd = ld2(p, 6), pe = ld2(p, 8);
        const float2 ta = ld2(t, 0), tb = ld2(t, 2), tc = ld2(t, 4),
                     td = ld2(t, 6), te = ld2(t, 8);

        // class loss (channels 10..29) -- consumed as loaded, nothing kept
        float l_class = 0.0f;
        #pragma unroll
        for (int c = 10; c < 30; c += 2) {
            const float2 pv = ld2(p, c);
            const float2 tv = ld2(t, c);
            const float d0 = pv.x - tv.x;
            const float d1 = pv.y - tv.y;
            l_class += d0 * d0 + d1 * d1;
        }

        const float obj   = (tc.x > 0.0f) ? 1.0f : 0.0f;   // t[4]
        const float noobj = 1.0f - obj;

        // no-object confidence loss (conf channels 4 and 9)
        const float d4 = pc.x - tc.x;   // p[4]-t[4]
        const float d9 = pe.y - te.y;   // p[9]-t[9]
        const float l_noobj = d4 * d4 + d9 * d9;

        // target box 0 -> xyxy (matches reference op order)
        const float t_x0 = ta.x / SDIV - 0.5f * tb.x;
        const float t_y0 = ta.y / SDIV - 0.5f * tb.y;
        const float t_x1 = ta.x / SDIV + 0.5f * tb.x;
        const float t_y1 = ta.y / SDIV + 0.5f * tb.y;
        const float area_t = (t_x1 - t_x0) * (t_y1 - t_y0);

        // pred box 0: ch 0..4 = pa.x pa.y pb.x pb.y pc.x
        float iou0;
        {
            const float x0 = pa.x / SDIV - 0.5f * pb.x;
            const float y0 = pa.y / SDIV - 0.5f * pb.y;
            const float x1 = pa.x / SDIV + 0.5f * pb.x;
            const float y1 = pa.y / SDIV + 0.5f * pb.y;
            const float ltx = fmaxf(x0, t_x0);
            const float lty = fmaxf(y0, t_y0);
            const float rbx = fminf(x1, t_x1);
            const float rby = fminf(y1, t_y1);
            const float w = fmaxf(rbx - ltx, 0.0f);
            const float h = fmaxf(rby - lty, 0.0f);
            const float inter  = w * h;
            const float area_p = (x1 - x0) * (y1 - y0);
            const float uni = fmaxf(area_p + area_t - inter, 1e-10f);
            iou0 = inter / uni;
        }
        // pred box 1: ch 5..9 = pc.y pd.x pd.y pe.x pe.y
        float iou1;
        {
            const float x0 = pc.y / SDIV - 0.5f * pd.y;
            const float y0 = pd.x / SDIV - 0.5f * pe.x;
            const float x1 = pc.y / SDIV + 0.5f * pd.y;
            const float y1 = pd.x / SDIV + 0.5f * pe.x;
            const float ltx = fmaxf(x0, t_x0);
            const float lty = fmaxf(y0, t_y0);
            const float rbx = fminf(x1, t_x1);
            const float rby = fminf(y1, t_y1);
            const float w = fmaxf(rbx - ltx, 0.0f);
            const float h = fmaxf(rby - lty, 0.0f);
            const float inter  = w * h;
            const float area_p = (x1 - x0) * (y1 - y0);
            const float uni = fmaxf(area_p + area_t - inter, 1e-10f);
            iou1 = inter / uni;
        }

        // jnp.argmax picks first on ties -> box1 only if strictly greater
        const bool  bsel    = (iou1 > iou0);
        const float max_iou = bsel ? iou1 : iou0;

        // responsible pred box channels
        const float prx = bsel ? pc.y : pa.x;
        const float pry = bsel ? pd.x : pa.y;
        const float prw = bsel ? pd.y : pb.x;
        const float prh = bsel ? pe.x : pb.y;
        const float prc = bsel ? pe.y : pc.x;
        // responsible target box channels
        const float trx = bsel ? tc.y : ta.x;
        const float try_ = bsel ? td.x : ta.y;
        const float trw = bsel ? td.y : tb.x;
        const float trh = bsel ? te.x : tb.y;

        const float dx = prx - trx;
        const float dy = pry - try_;
        const float l_xy = dx * dx + dy * dy;
        const float dw = sqrtf(prw) - sqrtf(trw);
        const float dh = sqrtf(prh) - sqrtf(trh);
        const float l_wh = dw * dw + dh * dh;
        const float dc = prc - max_iou;
        const float l_obj = dc * dc;

        cell_loss = obj * (5.0f * (l_xy + l_wh) + l_obj + l_class)
                  + 0.5f * noobj * l_noobj;
    }

    // ---- reduce: wave64 shuffle -> per-wave LDS -> per-block result ----
    float v = cell_loss;
    #pragma unroll
    for (int off = 32; off > 0; off >>= 1)
        v += __shfl_down(v, off, 64);

    const int wave = tid >> 6;
    const int lane = tid & 63;
    if (lane == 0) wsums[wave] = v;
    __syncthreads();
    if (tid == 0) {
        const float s = wsums[0] + wsums[1] + wsums[2] + wsums[3];
        if (USE_ATOMIC) atomicAdd(dst, s * scale);
        else            dst[blockIdx.x] = s;
    }
}

__global__ __launch_bounds__(256) void yolo_loss_pass2(
    const float* __restrict__ partials, float* __restrict__ out,
    int n_partials, float scale)
{
    __shared__ float wsums[4];
    const int tid = threadIdx.x;

    float v = 0.0f;
    for (int i = tid; i < n_partials; i += 256)
        v += partials[i];

    #pragma unroll
    for (int off = 32; off > 0; off >>= 1)
        v += __shfl_down(v, off, 64);

    const int wave = tid >> 6;
    const int lane = tid & 63;
    if (lane == 0) wsums[wave] = v;
    __syncthreads();
    if (tid == 0)
        out[0] = (wsums[0] + wsums[1] + wsums[2] + wsums[3]) * scale;
}

__global__ __launch_bounds__(64) void zero_out_kernel(float* out) {
    if (threadIdx.x == 0) out[0] = 0.0f;
}

extern "C" void kernel_launch(void* const* d_in, const int* in_sizes, int n_in,
                              void* d_out, int out_size, void* d_ws, size_t ws_size,
                              hipStream_t stream) {
    const float* pred = (const float*)d_in[0];
    const float* tgt  = (const float*)d_in[1];
    float* out = (float*)d_out;
    float* partials = (float*)d_ws;

    const long long total   = (long long)in_sizes[0];
    const long long n_cells = total / CH;          // bs*S*S
    const long long bs      = n_cells / 49;        // S*S = 49
    const float scale = 1.0f / (float)bs;

    const int grid = (int)((n_cells + 255) / 256);

    if (ws_size >= (size_t)grid * sizeof(float)) {
        // deterministic two-pass path
        yolo_loss_pass1<false><<<grid, 256, 0, stream>>>(pred, tgt, partials,
                                                         n_cells, scale);
        yolo_loss_pass2<<<1, 256, 0, stream>>>(partials, out, grid, scale);
    } else {
        // fallback: zero-init + one atomic per block
        zero_out_kernel<<<1, 64, 0, stream>>>(out);
        yolo_loss_pass1<true><<<grid, 256, 0, stream>>>(pred, tgt, out,
                                                        n_cells, scale);
    }
}